// Round 1
// baseline (1313.004 us; speedup 1.0000x reference)
//
#include <hip/hip_runtime.h>
#include <hip/hip_bf16.h>

typedef long long ll;

// ---- problem constants ----
// B_=512, N=49, C=256, H=8, hd=32, rB=8, n_rf=64, nW=64, NPIX=64*49=3136
#define SCALE 0.17677669529663687f

// ---- workspace layout (float offsets) ----
static const ll FLAG_OFF = 0;
static const ll QKV_OFF  = 256;                       // 25088*768 = 19267584
static const ll RAW_OFF  = QKV_OFF + 19267584LL;      // 512*512   = 262144
static const ll REFQ_OFF = RAW_OFF + 262144LL;        // 131072
static const ll REFV_OFF = REFQ_OFF + 131072LL;       // 131072
static const ll R_OFF    = REFV_OFF + 131072LL;       // 12845056
static const ll U_OFF    = R_OFF + 12845056LL;        // 12845056
static const ll PART_OFF = U_OFF + 12845056LL;        // 8*196*8*2 = 25088
static const ll STAT_OFF = PART_OFF + 25088LL;        // 128
static const ll QN_OFF   = STAT_OFF + 128LL;          // 6422528
static const ll PP_OFF   = U_OFF;                     // alias (u dead after last apply)

__device__ __forceinline__ float ldin(const void* p, ll i, int isbf) {
  if (isbf) return __bfloat162float(((const __hip_bfloat16*)p)[i]);
  return ((const float*)p)[i];
}
__device__ __forceinline__ void stout(void* p, ll i, float v, int isbf) {
  if (isbf) ((__hip_bfloat16*)p)[i] = __float2bfloat16(v);
  else ((float*)p)[i] = v;
}

// Detect whether inputs are bf16 pairs or f32 by testing low 16 bits of x.
__global__ void k_detect(const unsigned int* x, int* flag) {
  if (threadIdx.x == 0 && blockIdx.x == 0) {
    int votes = 0;
    for (int i = 0; i < 16; ++i) {
      unsigned int lo = x[i] & 0xFFFFu;
      int e = (int)((lo >> 7) & 0xFFu);
      if (e >= 104 && e <= 144) votes++;   // plausible |v| in [2^-23, 2^17]
    }
    *flag = (votes >= 12) ? 1 : 0;
  }
}

// Tiled f32 GEMM: C[M,Nn] = A[M,K] @ B[K,Nn] + bias[Nn]
// amode: 1 -> A is external input (dtype per flag), 0 -> A is f32 ws
// cmode: 1 -> C is d_out (dtype per flag),          0 -> C is f32 ws
__global__ __launch_bounds__(256) void k_gemm64(
    const void* A, const void* B, const void* bias, void* C,
    int M, int K, int Nn, int amode, int cmode, const int* flagp) {
  const int isbf = *flagp;
  __shared__ float As[16][65];
  __shared__ float Bs[16][65];
  const int tx = threadIdx.x, ty = threadIdx.y;
  const int t = ty * 16 + tx;
  const int m0 = blockIdx.x * 64, n0 = blockIdx.y * 64;
  float acc[4][4] = {};
  for (int k0 = 0; k0 < K; k0 += 16) {
    for (int i = t; i < 1024; i += 256) {
      int mm = i >> 4, kk = i & 15;
      float v;
      if (amode) v = ldin(A, (ll)(m0 + mm) * K + (k0 + kk), isbf);
      else       v = ((const float*)A)[(ll)(m0 + mm) * K + (k0 + kk)];
      As[kk][mm] = v;
    }
    for (int i = t; i < 1024; i += 256) {
      int kk = i >> 6, nn = i & 63;
      Bs[kk][nn] = ldin(B, (ll)(k0 + kk) * Nn + (n0 + nn), isbf);
    }
    __syncthreads();
#pragma unroll
    for (int kk = 0; kk < 16; ++kk) {
      float av[4], bv[4];
#pragma unroll
      for (int a = 0; a < 4; ++a) av[a] = As[kk][ty * 4 + a];
#pragma unroll
      for (int b = 0; b < 4; ++b) bv[b] = Bs[kk][tx * 4 + b];
#pragma unroll
      for (int a = 0; a < 4; ++a)
#pragma unroll
        for (int b = 0; b < 4; ++b) acc[a][b] += av[a] * bv[b];
    }
    __syncthreads();
  }
  for (int a = 0; a < 4; ++a) {
    int row = m0 + ty * 4 + a;
    for (int b = 0; b < 4; ++b) {
      int col = n0 + tx * 4 + b;
      float v = acc[a][b] + ldin(bias, col, isbf);
      if (cmode) stout(C, (ll)row * Nn + col, v, isbf);
      else ((float*)C)[(ll)row * Nn + col] = v;
    }
  }
}

// ref_q = diff_mu + exp(diff_logsigma)*raw[:,:,0:256]; ref_v = raw[:,:,256:512]
// layout out: [rb][h][m][d]
__global__ __launch_bounds__(256) void k_refqk_post(
    const float* raw, const void* mu, const void* ls,
    float* refq, float* refv, const int* flagp) {
  const int isbf = *flagp;
  int i = blockIdx.x * 256 + threadIdx.x;   // 131072 total
  if (i >= 131072) return;
  int c = i & 255, m = (i >> 8) & 63, rb = i >> 14;
  int h = c >> 5, d = c & 31;
  float q = raw[(ll)(rb * 64 + m) * 512 + c];
  float v = raw[(ll)(rb * 64 + m) * 512 + 256 + c];
  q = ldin(mu, c, isbf) + __expf(ldin(ls, c, isbf)) * q;
  ll o = ((ll)((rb * 8 + h) * 64 + m)) * 32 + d;
  refq[o] = q;
  refv[o] = v;
}

// r[rb][h][w*49+n][m] = scale * q[b,h,n,:] . ref_q[rb,h,m,:]
__global__ __launch_bounds__(256) void k_refattn(
    const float* qkv, const float* refq, float* r) {
  const int bid = blockIdx.x;        // 4096 = b*8+h
  const int b = bid >> 3, h = bid & 7;
  const int rb = b >> 6, w = b & 63;
  __shared__ float qs[49][32];
  __shared__ float rk[64][33];
  const int t = threadIdx.x;
  for (int i = t; i < 49 * 32; i += 256) {
    int n = i >> 5, d = i & 31;
    qs[n][d] = qkv[(ll)(b * 49 + n) * 768 + h * 32 + d] * SCALE;
  }
  for (int i = t; i < 64 * 32; i += 256) {
    int m = i >> 5, d = i & 31;
    rk[m][d] = refq[((ll)((rb * 8 + h) * 64 + m)) * 32 + d];
  }
  __syncthreads();
  const ll base = ((ll)(rb * 8 + h) * 3136 + (ll)w * 49) * 64;
  for (int o = t; o < 3136; o += 256) {
    int n = o >> 6, m = o & 63;
    float s = 0.f;
#pragma unroll
    for (int d = 0; d < 32; ++d) s += qs[n][d] * rk[m][d];
    r[base + (ll)n * 64 + m] = s;
  }
}

// 3x3 SAME conv over (batch=8, ch=8, H=3136, W=64) + bias, fused partial LN sums
__global__ __launch_bounds__(256) void k_conv(
    const float* r, const void* cw, const void* cb, float* u,
    float* part, const int* flagp) {
  const int isbf = *flagp;
  const int b = blockIdx.y, yt = blockIdx.x;   // 8 x 196
  const int y0 = yt * 16;
  __shared__ float in_s[8][18][64];
  __shared__ float w_s[576];
  const int t = threadIdx.x;
  for (int i = t; i < 576; i += 256) w_s[i] = ldin(cw, i, isbf);
  for (int i = t; i < 8 * 18 * 64; i += 256) {
    int ch = i / 1152, rem = i - ch * 1152;
    int row = rem >> 6, col = rem & 63;
    int gy = y0 - 1 + row;
    float v = 0.f;
    if (gy >= 0 && gy < 3136)
      v = r[((ll)(b * 8 + ch) * 3136 + gy) * 64 + col];
    in_s[ch][row][col] = v;
  }
  __syncthreads();
  const int oc = t >> 5, l = t & 31;
  const float bias = ldin(cb, oc, isbf);
  float lsum = 0.f, lsq = 0.f;
  for (int j = 0; j < 32; ++j) {
    int pix = l + (j << 5);
    int ry = pix >> 6, xx = pix & 63;
    float acc = bias;
#pragma unroll
    for (int ic = 0; ic < 8; ++ic) {
#pragma unroll
      for (int ky = 0; ky < 3; ++ky) {
        const float* row = in_s[ic][ry + ky];
        const float* wr = &w_s[((oc * 8 + ic) * 3 + ky) * 3];
        float lft = (xx > 0) ? row[xx - 1] : 0.f;
        float mid = row[xx];
        float rgt = (xx < 63) ? row[xx + 1] : 0.f;
        acc += lft * wr[0] + mid * wr[1] + rgt * wr[2];
      }
    }
    u[((ll)(b * 8 + oc) * 3136 + (y0 + ry)) * 64 + xx] = acc;
    lsum += acc; lsq += acc * acc;
  }
  for (int off = 16; off > 0; off >>= 1) {
    lsum += __shfl_down(lsum, off, 32);
    lsq  += __shfl_down(lsq, off, 32);
  }
  if (l == 0) {
    ll pi = ((ll)(b * 196 + yt) * 8 + oc) * 2;
    part[pi] = lsum; part[pi + 1] = lsq;
  }
}

__global__ __launch_bounds__(64) void k_stats(const float* part, float* stat) {
  int g = threadIdx.x;   // 64 groups = (batch, oc)
  int b = g >> 3, oc = g & 7;
  float s = 0.f, sq = 0.f;
  for (int t2 = 0; t2 < 196; ++t2) {
    ll pi = ((ll)(b * 196 + t2) * 8 + oc) * 2;
    s  += part[pi];
    sq += part[pi + 1];
  }
  float mu = s / 200704.0f;
  float var = sq / 200704.0f - mu * mu;
  stat[g * 2] = mu;
  stat[g * 2 + 1] = rsqrtf(var + 1e-5f);
}

__global__ __launch_bounds__(256) void k_apply(
    const float* u, float* r, const float* stat) {
  int g = blockIdx.y;                              // 64 groups
  int i = blockIdx.x * 256 + threadIdx.x;          // 784*256 = 200704
  ll idx = (ll)g * 200704 + i;
  float mu = stat[g * 2], istd = stat[g * 2 + 1];
  float x = (u[idx] - mu) * istd;
  float gl = 0.5f * x * (1.0f + erff(x * 0.70710678118654752f));
  r[idx] += gl;
}

// softmax over 64 refs + q_new = p . ref_v * scale
__global__ __launch_bounds__(64) void k_smqn(
    const float* r, const float* refv, float* qn) {
  const int bid = blockIdx.x;
  const int b = bid >> 3, h = bid & 7;
  const int rb = b >> 6, w = b & 63;
  const int lane = threadIdx.x;
  __shared__ float vs[64][32];
  __shared__ float ps[64];
  for (int i = lane; i < 2048; i += 64) {
    int m = i >> 5, d = i & 31;
    vs[m][d] = refv[((ll)((rb * 8 + h) * 64 + m)) * 32 + d];
  }
  __syncthreads();
  const ll rbase = ((ll)(rb * 8 + h) * 3136 + (ll)w * 49) * 64;
  const ll qbase = (ll)(b * 8 + h) * 49 * 32;
  for (int n = 0; n < 49; ++n) {
    float s = r[rbase + n * 64 + lane];
    float mx = s;
    for (int off = 32; off > 0; off >>= 1) mx = fmaxf(mx, __shfl_xor(mx, off));
    float e = expf(s - mx);
    float sum = e;
    for (int off = 32; off > 0; off >>= 1) sum += __shfl_xor(sum, off);
    ps[lane] = e / sum;
    __syncthreads();
    if (lane < 32) {
      float acc = 0.f;
      for (int m = 0; m < 64; ++m) acc += ps[m] * vs[m][lane];
      qn[qbase + n * 32 + lane] = acc * SCALE;
    }
    __syncthreads();
  }
}

// attn = qn.k^T + rpb + mask -> softmax -> .v -> preproj[(b*49+n)*256 + h*32+d]
__global__ __launch_bounds__(64) void k_attn(
    const float* qkv, const float* qn, const void* table, const void* mask,
    float* pp, const int* flagp) {
  const int isbf = *flagp;
  const int bid = blockIdx.x;
  const int b = bid >> 3, h = bid & 7;
  const int w = b & 63;
  const int lane = threadIdx.x;
  __shared__ float ks[49][33];
  __shared__ float vs[49][33];
  __shared__ float qs[49][32];
  __shared__ float msk[49][49];
  __shared__ float tbl[169];
  __shared__ float ps[64];
  for (int i = lane; i < 49 * 32; i += 64) {
    int n = i >> 5, d = i & 31;
    ks[n][d] = qkv[(ll)(b * 49 + n) * 768 + 256 + h * 32 + d];
    vs[n][d] = qkv[(ll)(b * 49 + n) * 768 + 512 + h * 32 + d];
    qs[n][d] = qn[((ll)(b * 8 + h) * 49 + n) * 32 + d];
  }
  for (int i = lane; i < 169; i += 64) tbl[i] = ldin(table, (ll)i * 8 + h, isbf);
  for (int i = lane; i < 2401; i += 64) {
    int n = i / 49, m = i - n * 49;
    msk[n][m] = ldin(mask, (ll)w * 2401 + i, isbf);
  }
  __syncthreads();
  const int my = (lane < 49) ? (lane / 7) : 0;
  const int mx2 = (lane < 49) ? (lane % 7) : 0;
  for (int n = 0; n < 49; ++n) {
    float s = -1e30f;
    if (lane < 49) {
      float acc = 0.f;
#pragma unroll
      for (int d = 0; d < 32; ++d) acc += qs[n][d] * ks[lane][d];
      int dy = n / 7 - my + 6, dx = n % 7 - mx2 + 6;
      acc += tbl[dy * 13 + dx] + msk[n][lane];
      s = acc;
    }
    float mx = s;
    for (int off = 32; off > 0; off >>= 1) mx = fmaxf(mx, __shfl_xor(mx, off));
    float e = (lane < 49) ? expf(s - mx) : 0.f;
    float sum = e;
    for (int off = 32; off > 0; off >>= 1) sum += __shfl_xor(sum, off);
    ps[lane] = (sum > 0.f) ? (e / sum) : 0.f;
    __syncthreads();
    if (lane < 32) {
      float acc = 0.f;
      for (int m = 0; m < 49; ++m) acc += ps[m] * vs[m][lane];
      pp[(ll)(b * 49 + n) * 256 + h * 32 + lane] = acc;
    }
    __syncthreads();
  }
}

__global__ __launch_bounds__(256) void k_tokens(
    const void* dep, const void* seg, void* out, const int* flagp) {
  const int isbf = *flagp;
  int i = blockIdx.x * 256 + threadIdx.x;   // 4096
  if (i < 2048)       stout(out, 6422528LL + i, ldin(dep, i, isbf), isbf);
  else if (i < 4096)  stout(out, 6422528LL + i, ldin(seg, i - 2048, isbf), isbf);
}

extern "C" void kernel_launch(void* const* d_in, const int* in_sizes, int n_in,
                              void* d_out, int out_size, void* d_ws, size_t ws_size,
                              hipStream_t stream) {
  (void)in_sizes; (void)n_in; (void)out_size; (void)ws_size;
  float* ws = (float*)d_ws;
  int* flag = (int*)d_ws;
  const void* x      = d_in[0];
  const void* mask   = d_in[1];
  const void* x_ref  = d_in[2];
  const void* dep    = d_in[3];
  const void* seg    = d_in[4];
  const void* dmu    = d_in[5];
  const void* dls    = d_in[6];
  const void* rpb    = d_in[7];
  const void* qkv_w  = d_in[8];
  const void* qkv_b  = d_in[9];
  const void* rqk_w  = d_in[10];
  const void* rqk_b  = d_in[11];
  const void* conv_w = d_in[12];
  const void* conv_b = d_in[13];
  const void* proj_w = d_in[14];
  const void* proj_b = d_in[15];

  float* QKV  = ws + QKV_OFF;
  float* RAW  = ws + RAW_OFF;
  float* REFQ = ws + REFQ_OFF;
  float* REFV = ws + REFV_OFF;
  float* R    = ws + R_OFF;
  float* U    = ws + U_OFF;
  float* PART = ws + PART_OFF;
  float* STAT = ws + STAT_OFF;
  float* QN   = ws + QN_OFF;
  float* PP   = ws + PP_OFF;

  k_detect<<<dim3(1), dim3(64), 0, stream>>>((const unsigned int*)x, flag);
  k_gemm64<<<dim3(392, 12), dim3(16, 16), 0, stream>>>(
      x, qkv_w, qkv_b, QKV, 25088, 256, 768, 1, 0, flag);
  k_gemm64<<<dim3(8, 8), dim3(16, 16), 0, stream>>>(
      x_ref, rqk_w, rqk_b, RAW, 512, 256, 512, 1, 0, flag);
  k_refqk_post<<<dim3(512), dim3(256), 0, stream>>>(RAW, dmu, dls, REFQ, REFV, flag);
  k_refattn<<<dim3(4096), dim3(256), 0, stream>>>(QKV, REFQ, R);
  for (int it = 0; it < 3; ++it) {
    k_conv<<<dim3(196, 8), dim3(256), 0, stream>>>(R, conv_w, conv_b, U, PART, flag);
    k_stats<<<dim3(1), dim3(64), 0, stream>>>(PART, STAT);
    k_apply<<<dim3(784, 64), dim3(256), 0, stream>>>(U, R, STAT);
  }
  k_smqn<<<dim3(4096), dim3(64), 0, stream>>>(R, REFV, QN);
  k_attn<<<dim3(4096), dim3(64), 0, stream>>>(QKV, QN, rpb, mask, PP, flag);
  k_gemm64<<<dim3(392, 4), dim3(16, 16), 0, stream>>>(
      PP, proj_w, proj_b, d_out, 25088, 256, 256, 0, 1, flag);
  k_tokens<<<dim3(16), dim3(256), 0, stream>>>(dep, seg, d_out, flag);
}

// Round 2
// 903.444 us; speedup vs baseline: 1.4533x; 1.4533x over previous
//
#include <hip/hip_runtime.h>
#include <hip/hip_bf16.h>

typedef long long ll;

// ---- problem constants ----
// B_=512, N=49, C=256, H=8, hd=32, rB=8, n_rf=64, nW=64, NPIX=64*49=3136
#define SCALE 0.17677669529663687f

// ---- workspace layout (float offsets) ----
static const ll QKV_OFF  = 256;                       // 25088*768 = 19267584
static const ll RAW_OFF  = QKV_OFF + 19267584LL;      // 512*512   = 262144
static const ll REFQ_OFF = RAW_OFF + 262144LL;        // 131072
static const ll REFV_OFF = REFQ_OFF + 131072LL;       // 131072
static const ll R_OFF    = REFV_OFF + 131072LL;       // 12845056
static const ll U_OFF    = R_OFF + 12845056LL;        // 12845056
static const ll PART_OFF = U_OFF + 12845056LL;        // 8*196*8*2 = 25088
static const ll STAT_OFF = PART_OFF + 25088LL;        // 128
static const ll PP_OFF   = U_OFF;                     // alias (u dead after last apply)

__device__ __forceinline__ float ldin(const void* p, ll i, int isbf) {
  if (isbf) return __bfloat162float(((const __hip_bfloat16*)p)[i]);
  return ((const float*)p)[i];
}
__device__ __forceinline__ void stout(void* p, ll i, float v, int isbf) {
  if (isbf) ((__hip_bfloat16*)p)[i] = __float2bfloat16(v);
  else ((float*)p)[i] = v;
}

// Detect whether inputs are bf16 pairs or f32 by testing low 16 bits of x.
__global__ void k_detect(const unsigned int* x, int* flag) {
  if (threadIdx.x == 0 && blockIdx.x == 0) {
    int votes = 0;
    for (int i = 0; i < 16; ++i) {
      unsigned int lo = x[i] & 0xFFFFu;
      int e = (int)((lo >> 7) & 0xFFu);
      if (e >= 104 && e <= 144) votes++;
    }
    *flag = (votes >= 12) ? 1 : 0;
  }
}

// Tiled f32 GEMM: C[M,Nn] = A[M,K] @ B[K,Nn] + bias[Nn]
// amode: 1 -> A is external input (dtype per flag), 0 -> A is f32 ws
// cmode: 1 -> C is d_out (dtype per flag),          0 -> C is f32 ws
__global__ __launch_bounds__(256) void k_gemm64(
    const void* A, const void* B, const void* bias, void* C,
    int M, int K, int Nn, int amode, int cmode, const int* flagp) {
  const int isbf = *flagp;
  __shared__ float As[16][68];   // 68 stride -> 16B-aligned rows
  __shared__ float Bs[16][68];
  const int tx = threadIdx.x, ty = threadIdx.y;
  const int t = ty * 16 + tx;
  const int m0 = blockIdx.x * 64, n0 = blockIdx.y * 64;
  const bool a_f32 = (amode == 0) || (!isbf);
  const bool b_f32 = !isbf;
  float acc[4][4] = {};
  for (int k0 = 0; k0 < K; k0 += 16) {
    if (a_f32) {
      int mm = t >> 2, kk0 = (t & 3) * 4;
      const float* ap = (const float*)A + (ll)(m0 + mm) * K + k0 + kk0;
      float4 a4 = *(const float4*)ap;
      As[kk0 + 0][mm] = a4.x; As[kk0 + 1][mm] = a4.y;
      As[kk0 + 2][mm] = a4.z; As[kk0 + 3][mm] = a4.w;
    } else {
      for (int i = t; i < 1024; i += 256) {
        int mm = i >> 4, kk = i & 15;
        As[kk][mm] = ldin(A, (ll)(m0 + mm) * K + (k0 + kk), 1);
      }
    }
    if (b_f32) {
      int kk = t >> 4, nn0 = (t & 15) * 4;
      const float* bp = (const float*)B + (ll)(k0 + kk) * Nn + n0 + nn0;
      *(float4*)&Bs[kk][nn0] = *(const float4*)bp;
    } else {
      for (int i = t; i < 1024; i += 256) {
        int kk = i >> 6, nn = i & 63;
        Bs[kk][nn] = ldin(B, (ll)(k0 + kk) * Nn + (n0 + nn), 1);
      }
    }
    __syncthreads();
#pragma unroll
    for (int kk = 0; kk < 16; ++kk) {
      float4 a4 = *(const float4*)&As[kk][ty * 4];
      float4 b4 = *(const float4*)&Bs[kk][tx * 4];
      float av[4] = {a4.x, a4.y, a4.z, a4.w};
      float bv[4] = {b4.x, b4.y, b4.z, b4.w};
#pragma unroll
      for (int a = 0; a < 4; ++a)
#pragma unroll
        for (int b = 0; b < 4; ++b) acc[a][b] += av[a] * bv[b];
    }
    __syncthreads();
  }
  for (int a = 0; a < 4; ++a) {
    int row = m0 + ty * 4 + a;
    if (cmode && isbf) {
      for (int b = 0; b < 4; ++b) {
        int col = n0 + tx * 4 + b;
        stout(C, (ll)row * Nn + col, acc[a][b] + ldin(bias, col, isbf), 1);
      }
    } else {
      int col = n0 + tx * 4;
      float4 o;
      o.x = acc[a][0] + ldin(bias, col + 0, isbf);
      o.y = acc[a][1] + ldin(bias, col + 1, isbf);
      o.z = acc[a][2] + ldin(bias, col + 2, isbf);
      o.w = acc[a][3] + ldin(bias, col + 3, isbf);
      *(float4*)&((float*)C)[(ll)row * Nn + col] = o;
    }
  }
}

// ref_q = diff_mu + exp(diff_logsigma)*raw[:,:,0:256]; ref_v = raw[:,:,256:512]
// layout out: [rb][h][m][d]
__global__ __launch_bounds__(256) void k_refqk_post(
    const float* raw, const void* mu, const void* ls,
    float* refq, float* refv, const int* flagp) {
  const int isbf = *flagp;
  int i = blockIdx.x * 256 + threadIdx.x;
  if (i >= 131072) return;
  int c = i & 255, m = (i >> 8) & 63, rb = i >> 14;
  int h = c >> 5, d = c & 31;
  float q = raw[(ll)(rb * 64 + m) * 512 + c];
  float v = raw[(ll)(rb * 64 + m) * 512 + 256 + c];
  q = ldin(mu, c, isbf) + __expf(ldin(ls, c, isbf)) * q;
  ll o = ((ll)((rb * 8 + h) * 64 + m)) * 32 + d;
  refq[o] = q;
  refv[o] = v;
}

// r[rb][h][w*49+n][m] = scale * q[b,h,n,:] . ref_q[rb,h,m,:]
__global__ __launch_bounds__(256) void k_refattn(
    const float* qkv, const float* refq, float* r) {
  const int bid = blockIdx.x;        // 4096 = b*8+h
  const int b = bid >> 3, h = bid & 7;
  const int rb = b >> 6, w = b & 63;
  __shared__ float qs[49][32];
  __shared__ float rk[64][33];
  const int t = threadIdx.x;
  for (int i = t; i < 49 * 32; i += 256) {
    int n = i >> 5, d = i & 31;
    qs[n][d] = qkv[(ll)(b * 49 + n) * 768 + h * 32 + d] * SCALE;
  }
  for (int i = t; i < 64 * 32; i += 256) {
    int m = i >> 5, d = i & 31;
    rk[m][d] = refq[((ll)((rb * 8 + h) * 64 + m)) * 32 + d];
  }
  __syncthreads();
  const ll base = ((ll)(rb * 8 + h) * 3136 + (ll)w * 49) * 64;
  for (int o = t; o < 3136; o += 256) {
    int n = o >> 6, m = o & 63;
    float s = 0.f;
#pragma unroll
    for (int d = 0; d < 32; ++d) s += qs[n][d] * rk[m][d];
    r[base + (ll)n * 64 + m] = s;
  }
}

// 3x3 SAME conv over (batch=8, ch=8, H=3136, W=64) + bias, fused partial LN sums
__global__ __launch_bounds__(256) void k_conv(
    const float* r, const void* cw, const void* cb, float* u,
    float* part, const int* flagp) {
  const int isbf = *flagp;
  const int b = blockIdx.y, yt = blockIdx.x;   // 8 x 196
  const int y0 = yt * 16;
  __shared__ float in_s[8][18][64];
  __shared__ float w_s[576];
  const int t = threadIdx.x;
  for (int i = t; i < 576; i += 256) w_s[i] = ldin(cw, i, isbf);
  for (int i = t; i < 8 * 18 * 64; i += 256) {
    int ch = i / 1152, rem = i - ch * 1152;
    int row = rem >> 6, col = rem & 63;
    int gy = y0 - 1 + row;
    float v = 0.f;
    if (gy >= 0 && gy < 3136)
      v = r[((ll)(b * 8 + ch) * 3136 + gy) * 64 + col];
    in_s[ch][row][col] = v;
  }
  __syncthreads();
  const int oc = t >> 5, l = t & 31;
  const float bias = ldin(cb, oc, isbf);
  float lsum = 0.f, lsq = 0.f;
  for (int j = 0; j < 32; ++j) {
    int pix = l + (j << 5);
    int ry = pix >> 6, xx = pix & 63;
    float acc = bias;
#pragma unroll
    for (int ic = 0; ic < 8; ++ic) {
#pragma unroll
      for (int ky = 0; ky < 3; ++ky) {
        const float* row = in_s[ic][ry + ky];
        const float* wr = &w_s[((oc * 8 + ic) * 3 + ky) * 3];
        float lft = (xx > 0) ? row[xx - 1] : 0.f;
        float mid = row[xx];
        float rgt = (xx < 63) ? row[xx + 1] : 0.f;
        acc += lft * wr[0] + mid * wr[1] + rgt * wr[2];
      }
    }
    u[((ll)(b * 8 + oc) * 3136 + (y0 + ry)) * 64 + xx] = acc;
    lsum += acc; lsq += acc * acc;
  }
  for (int off = 16; off > 0; off >>= 1) {
    lsum += __shfl_down(lsum, off, 32);
    lsq  += __shfl_down(lsq, off, 32);
  }
  if (l == 0) {
    ll pi = ((ll)(b * 196 + yt) * 8 + oc) * 2;
    part[pi] = lsum; part[pi + 1] = lsq;
  }
}

__global__ __launch_bounds__(64) void k_stats(const float* part, float* stat) {
  int g = threadIdx.x;   // 64 groups = (batch, oc)
  int b = g >> 3, oc = g & 7;
  float s = 0.f, sq = 0.f;
  for (int t2 = 0; t2 < 196; ++t2) {
    ll pi = ((ll)(b * 196 + t2) * 8 + oc) * 2;
    s  += part[pi];
    sq += part[pi + 1];
  }
  float mu = s / 200704.0f;
  float var = sq / 200704.0f - mu * mu;
  stat[g * 2] = mu;
  stat[g * 2 + 1] = rsqrtf(var + 1e-5f);
}

__global__ __launch_bounds__(256) void k_apply(
    const float* u, float* r, const float* stat) {
  int g = blockIdx.y;                              // 64 groups
  int i = blockIdx.x * 256 + threadIdx.x;          // 784*256 = 200704
  ll idx = (ll)g * 200704 + i;
  float mu = stat[g * 2], istd = stat[g * 2 + 1];
  float x = (u[idx] - mu) * istd;
  float gl = 0.5f * x * (1.0f + erff(x * 0.70710678118654752f));
  r[idx] += gl;
}

// Fused: ref-softmax + q_new + window attention (rpb+mask) + PV
// one block of 256 threads per (b,h)
__global__ __launch_bounds__(256) void k_fused(
    const float* qkv, const float* r, const float* refv,
    const void* table, const void* mask, float* pp, const int* flagp) {
  const int isbf = *flagp;
  const int bid = blockIdx.x;           // 4096 = b*8+h
  const int b = bid >> 3, h = bid & 7;
  const int rb = b >> 6, w = b & 63;
  const int t = threadIdx.x;
  const int wid = t >> 6, lane = t & 63;
  __shared__ float ks[49][33];
  __shared__ float vs[49][36];          // 36: 16B-aligned rows for float4
  __shared__ float rv[64][36];
  __shared__ float qn[49][36];
  __shared__ float ps[49][66];          // 66: break bank-aliasing on column reads
  __shared__ float msk[49][49];
  __shared__ float tbl[169];
  for (int i = t; i < 49 * 32; i += 256) {
    int n = i >> 5, d = i & 31;
    ks[n][d] = qkv[(ll)(b * 49 + n) * 768 + 256 + h * 32 + d];
    vs[n][d] = qkv[(ll)(b * 49 + n) * 768 + 512 + h * 32 + d];
  }
  for (int i = t; i < 64 * 32; i += 256) {
    int m = i >> 5, d = i & 31;
    rv[m][d] = refv[((ll)((rb * 8 + h) * 64 + m)) * 32 + d];
  }
  for (int i = t; i < 169; i += 256) tbl[i] = ldin(table, (ll)i * 8 + h, isbf);
  for (int i = t; i < 2401; i += 256) {
    int n = i / 49, m = i - n * 49;
    msk[n][m] = ldin(mask, (ll)w * 2401 + i, isbf);
  }
  __syncthreads();
  // phase A: softmax over 64 refs, rows split across 4 waves, lane = m
  const ll rbase = ((ll)(rb * 8 + h) * 3136 + (ll)w * 49) * 64;
  for (int n = wid; n < 49; n += 4) {
    float s = r[rbase + n * 64 + lane];
    float mx = s;
    for (int off = 32; off; off >>= 1) mx = fmaxf(mx, __shfl_xor(mx, off));
    float e = __expf(s - mx);
    float sum = e;
    for (int off = 32; off; off >>= 1) sum += __shfl_xor(sum, off);
    ps[n][lane] = e / sum;
  }
  __syncthreads();
  // phase B: q_new = p . ref_v * scale   (392 = 49n x 8 d-groups)
  for (int g = t; g < 392; g += 256) {
    int n = g >> 3, d0 = (g & 7) * 4;
    float ax = 0.f, ay = 0.f, az = 0.f, aw = 0.f;
    for (int m = 0; m < 64; ++m) {
      float p = ps[n][m];
      const float4 v4 = *(const float4*)&rv[m][d0];
      ax += p * v4.x; ay += p * v4.y; az += p * v4.z; aw += p * v4.w;
    }
    float4 o; o.x = ax * SCALE; o.y = ay * SCALE; o.z = az * SCALE; o.w = aw * SCALE;
    *(float4*)&qn[n][d0] = o;
  }
  __syncthreads();
  // phase C: scores = qn.k^T + rpb + mask  (2401 pairs)
  for (int pidx = t; pidx < 2401; pidx += 256) {
    int n = pidx / 49, m = pidx - n * 49;
    float acc = 0.f;
#pragma unroll
    for (int d = 0; d < 32; ++d) acc += qn[n][d] * ks[m][d];
    int dy = n / 7 - m / 7 + 6, dx = n % 7 - m % 7 + 6;
    ps[n][m] = acc + tbl[dy * 13 + dx] + msk[n][m];
  }
  __syncthreads();
  // phase D: softmax rows over 49
  for (int n = wid; n < 49; n += 4) {
    float s = (lane < 49) ? ps[n][lane] : -1e30f;
    float mx = s;
    for (int off = 32; off; off >>= 1) mx = fmaxf(mx, __shfl_xor(mx, off));
    float e = (lane < 49) ? __expf(s - mx) : 0.f;
    float sum = e;
    for (int off = 32; off; off >>= 1) sum += __shfl_xor(sum, off);
    ps[n][lane] = e / sum;
  }
  __syncthreads();
  // phase E: out = p . v  -> preproj
  for (int g = t; g < 392; g += 256) {
    int n = g >> 3, d0 = (g & 7) * 4;
    float ax = 0.f, ay = 0.f, az = 0.f, aw = 0.f;
    for (int m = 0; m < 49; ++m) {
      float p = ps[n][m];
      const float4 v4 = *(const float4*)&vs[m][d0];
      ax += p * v4.x; ay += p * v4.y; az += p * v4.z; aw += p * v4.w;
    }
    float4 o; o.x = ax; o.y = ay; o.z = az; o.w = aw;
    *(float4*)&pp[(ll)(b * 49 + n) * 256 + h * 32 + d0] = o;
  }
}

__global__ __launch_bounds__(256) void k_tokens(
    const void* dep, const void* seg, void* out, const int* flagp) {
  const int isbf = *flagp;
  int i = blockIdx.x * 256 + threadIdx.x;   // 4096
  if (i < 2048)       stout(out, 6422528LL + i, ldin(dep, i, isbf), isbf);
  else if (i < 4096)  stout(out, 6422528LL + i, ldin(seg, i - 2048, isbf), isbf);
}

extern "C" void kernel_launch(void* const* d_in, const int* in_sizes, int n_in,
                              void* d_out, int out_size, void* d_ws, size_t ws_size,
                              hipStream_t stream) {
  (void)in_sizes; (void)n_in; (void)out_size; (void)ws_size;
  float* ws = (float*)d_ws;
  int* flag = (int*)d_ws;
  const void* x      = d_in[0];
  const void* mask   = d_in[1];
  const void* x_ref  = d_in[2];
  const void* dep    = d_in[3];
  const void* seg    = d_in[4];
  const void* dmu    = d_in[5];
  const void* dls    = d_in[6];
  const void* rpb    = d_in[7];
  const void* qkv_w  = d_in[8];
  const void* qkv_b  = d_in[9];
  const void* rqk_w  = d_in[10];
  const void* rqk_b  = d_in[11];
  const void* conv_w = d_in[12];
  const void* conv_b = d_in[13];
  const void* proj_w = d_in[14];
  const void* proj_b = d_in[15];

  float* QKV  = ws + QKV_OFF;
  float* RAW  = ws + RAW_OFF;
  float* REFQ = ws + REFQ_OFF;
  float* REFV = ws + REFV_OFF;
  float* R    = ws + R_OFF;
  float* U    = ws + U_OFF;
  float* PART = ws + PART_OFF;
  float* STAT = ws + STAT_OFF;
  float* PP   = ws + PP_OFF;

  k_detect<<<dim3(1), dim3(64), 0, stream>>>((const unsigned int*)x, flag);
  k_gemm64<<<dim3(392, 12), dim3(16, 16), 0, stream>>>(
      x, qkv_w, qkv_b, QKV, 25088, 256, 768, 1, 0, flag);
  k_gemm64<<<dim3(8, 8), dim3(16, 16), 0, stream>>>(
      x_ref, rqk_w, rqk_b, RAW, 512, 256, 512, 1, 0, flag);
  k_refqk_post<<<dim3(512), dim3(256), 0, stream>>>(RAW, dmu, dls, REFQ, REFV, flag);
  k_refattn<<<dim3(4096), dim3(256), 0, stream>>>(QKV, REFQ, R);
  for (int it = 0; it < 3; ++it) {
    k_conv<<<dim3(196, 8), dim3(256), 0, stream>>>(R, conv_w, conv_b, U, PART, flag);
    k_stats<<<dim3(1), dim3(64), 0, stream>>>(PART, STAT);
    k_apply<<<dim3(784, 64), dim3(256), 0, stream>>>(U, R, STAT);
  }
  k_fused<<<dim3(4096), dim3(256), 0, stream>>>(QKV, R, REFV, rpb, mask, PP, flag);
  k_gemm64<<<dim3(392, 4), dim3(16, 16), 0, stream>>>(
      PP, proj_w, proj_b, d_out, 25088, 256, 256, 0, 1, flag);
  k_tokens<<<dim3(16), dim3(256), 0, stream>>>(dep, seg, d_out, flag);
}